// Round 2
// baseline (15060.851 us; speedup 1.0000x reference)
//
#include <hip/hip_runtime.h>

#define H 128
#define ED 64

// stats layout: [0:128) colsum, [128:256) colsumsq, [256:384) scale, [384:512) shift
__device__ __align__(16) float g_stats[512];

__global__ void k_zero_stats() {
    if (threadIdx.x < 512) g_stats[threadIdx.x] = 0.f;
}

// ================= CSR build =================
__global__ void k_hist(const int* __restrict__ ei, int* __restrict__ cnt, int E) {
    for (int e = blockIdx.x * blockDim.x + threadIdx.x; e < E;
         e += gridDim.x * blockDim.x)
        atomicAdd(&cnt[ei[E + e]], 1);
}

__global__ __launch_bounds__(1024) void k_scan(
    const int* __restrict__ cnt, int* __restrict__ off, int* __restrict__ cur,
    int N)
{
    __shared__ int part[1024];
    const int t = threadIdx.x;
    const int chunk = (N + 1023) >> 10;
    const int lo = t * chunk, hi = min(lo + chunk, N);
    int s = 0;
    for (int i = lo; i < hi; ++i) s += cnt[i];
    part[t] = s;
    __syncthreads();
    for (int d = 1; d < 1024; d <<= 1) {
        int v = (t >= d) ? part[t - d] : 0;
        __syncthreads();
        part[t] += v;
        __syncthreads();
    }
    int excl = (t == 0) ? 0 : part[t - 1];
    for (int i = lo; i < hi; ++i) {
        off[i] = excl; cur[i] = excl;
        excl += cnt[i];
    }
    if (t == 1023) off[N] = part[1023];
}

__global__ void k_fill(const int* __restrict__ ei, int* __restrict__ cur,
                       int* __restrict__ perm, int E) {
    for (int e = blockIdx.x * blockDim.x + threadIdx.x; e < E;
         e += gridDim.x * blockDim.x) {
        int pos = atomicAdd(&cur[ei[E + e]], 1);
        perm[pos] = e;
    }
}

// ================= Edge gather kernel =================
// one wave per dst node: agg[d] = sum_e relu(h[src_e] + ea[e]@We + be)
#define EB 8   // edges per wave-group
__global__ __launch_bounds__(256, 4) void k_edge_g(
    const float* __restrict__ hN, const int* __restrict__ ei,
    const float* __restrict__ ea, const float* __restrict__ We,
    const float* __restrict__ be,
    const int* __restrict__ off, const int* __restrict__ perm,
    float* __restrict__ agg, int N, int E)
{
    __shared__ __align__(16) float sW[ED * H];        // 32 KB
    __shared__ __align__(16) float sEA[4][EB][ED];    // 8 KB
    const int tid = threadIdx.x;
    for (int i = tid; i < (ED * H) / 4; i += 256)
        ((float4*)sW)[i] = ((const float4*)We)[i];
    __syncthreads();

    const int w = tid >> 6, lane = tid & 63;
    const int c = lane << 1;                          // columns {c, c+1}
    const float2 bb = *(const float2*)&be[c];
    const int waveId = (blockIdx.x << 2) | w;
    const int nWaves = gridDim.x << 2;

    for (int d = waveId; d < N; d += nWaves) {
        const int base = off[d], end = off[d + 1];
        float a0 = 0.f, a1 = 0.f;
        for (int e0 = base; e0 < end; e0 += EB) {
            const int m = end - e0;                   // valid edges this group
            int e4[EB];
#pragma unroll
            for (int j = 0; j < EB; ++j) {
                if (j < m) {
                    e4[j] = perm[e0 + j];
                    sEA[w][j][lane] = ea[(size_t)e4[j] * ED + lane];
                }
            }
            __builtin_amdgcn_wave_barrier();

            float ax[EB], ay[EB];
#pragma unroll
            for (int j = 0; j < EB; ++j) { ax[j] = bb.x; ay[j] = bb.y; }

#pragma unroll
            for (int k0 = 0; k0 < ED; k0 += 4) {
                float av[EB][4];
#pragma unroll
                for (int j = 0; j < EB; ++j) {
                    float4 t = *(const float4*)&sEA[w][j][k0];
                    av[j][0] = t.x; av[j][1] = t.y; av[j][2] = t.z; av[j][3] = t.w;
                }
#pragma unroll
                for (int kk = 0; kk < 4; ++kk) {
                    float2 wv = *(const float2*)&sW[(k0 + kk) * H + c];
#pragma unroll
                    for (int j = 0; j < EB; ++j) {
                        ax[j] = fmaf(av[j][kk], wv.x, ax[j]);
                        ay[j] = fmaf(av[j][kk], wv.y, ay[j]);
                    }
                }
            }

#pragma unroll
            for (int j = 0; j < EB; ++j) {
                if (j < m) {
                    int s = ei[e4[j]];
                    float2 hv = *(const float2*)&hN[(size_t)s * H + c];
                    a0 += fmaxf(ax[j] + hv.x, 0.f);
                    a1 += fmaxf(ay[j] + hv.y, 0.f);
                }
            }
            __builtin_amdgcn_wave_barrier();
        }
        float2 o; o.x = a0; o.y = a1;
        *(float2*)&agg[(size_t)d * H + c] = o;
    }
}

// ================= Fallback atomic edge kernel (small-ws path) =================
__global__ __launch_bounds__(256, 4) void k_edge(
    const float* __restrict__ hN, const int* __restrict__ ei,
    const float* __restrict__ ea, const float* __restrict__ We,
    const float* __restrict__ be, float* __restrict__ agg, int E)
{
    __shared__ __align__(16) float sW[ED * H];
    __shared__ __align__(16) float sEA[4][4][ED];
    const int tid = threadIdx.x;
    for (int i = tid; i < (ED * H) / 4; i += 256)
        ((float4*)sW)[i] = ((const float4*)We)[i];
    __syncthreads();
    const int w = tid >> 6, lane = tid & 63;
    const int c = lane << 1;
    const float2 bb = *(const float2*)&be[c];
    const int waveId = (blockIdx.x << 2) | w;
    const int nWaves = gridDim.x << 2;
    const int nGroups = (E + 3) >> 2;
    for (int g = waveId; g < nGroups; g += nWaves) {
        const int e0 = g << 2;
#pragma unroll
        for (int j = 0; j < 4; ++j) {
            int e = e0 + j;
            if (e < E) sEA[w][j][lane] = ea[(size_t)e * ED + lane];
        }
        __builtin_amdgcn_wave_barrier();
        float ax[4], ay[4];
#pragma unroll
        for (int j = 0; j < 4; ++j) { ax[j] = bb.x; ay[j] = bb.y; }
#pragma unroll
        for (int k0 = 0; k0 < ED; k0 += 4) {
            float av[4][4];
#pragma unroll
            for (int j = 0; j < 4; ++j) {
                float4 t = *(const float4*)&sEA[w][j][k0];
                av[j][0] = t.x; av[j][1] = t.y; av[j][2] = t.z; av[j][3] = t.w;
            }
#pragma unroll
            for (int kk = 0; kk < 4; ++kk) {
                float2 wv = *(const float2*)&sW[(k0 + kk) * H + c];
#pragma unroll
                for (int j = 0; j < 4; ++j) {
                    ax[j] = fmaf(av[j][kk], wv.x, ax[j]);
                    ay[j] = fmaf(av[j][kk], wv.y, ay[j]);
                }
            }
        }
#pragma unroll
        for (int j = 0; j < 4; ++j) {
            int e = e0 + j;
            if (e < E) {
                int s = ei[e];
                int d = ei[E + e];
                float2 hv = *(const float2*)&hN[(size_t)s * H + c];
                atomicAdd(&agg[(size_t)d * H + c],     fmaxf(ax[j] + hv.x, 0.f));
                atomicAdd(&agg[(size_t)d * H + c + 1], fmaxf(ay[j] + hv.y, 0.f));
            }
        }
        __builtin_amdgcn_wave_barrier();
    }
}

// ================= Node MLP kernel =================
__global__ __launch_bounds__(512, 2) void k_mlp(
    const float* __restrict__ hN, float* __restrict__ zb,
    const float* __restrict__ W1, const float* __restrict__ b1,
    const float* __restrict__ W2, const float* __restrict__ b2,
    const float* __restrict__ epsp, int N)
{
    __shared__ __align__(16) float sW1[H * H];
    __shared__ __align__(16) float sW2[H * H];
    __shared__ __align__(16) float sB[8][4][H];
    __shared__ float sRed[2 * H];
    const int tid = threadIdx.x;
    for (int i = tid; i < (H * H) / 4; i += 512) {
        ((float4*)sW1)[i] = ((const float4*)W1)[i];
        ((float4*)sW2)[i] = ((const float4*)W2)[i];
    }
    if (tid < 2 * H) sRed[tid] = 0.f;
    __syncthreads();

    const int w = tid >> 6, lane = tid & 63;
    const int c = lane << 1;
    const float e1 = 1.f + epsp[0];
    const float2 bb1 = *(const float2*)&b1[c];
    const float2 bb2 = *(const float2*)&b2[c];
    float s0 = 0.f, s1 = 0.f, q0 = 0.f, q1 = 0.f;

    const int waveId = (blockIdx.x << 3) | w;
    const int nWaves = gridDim.x << 3;
    const int nGroups = (N + 3) >> 2;

    for (int g = waveId; g < nGroups; g += nWaves) {
        const int n0 = g << 2;
#pragma unroll
        for (int j = 0; j < 4; ++j) {
            int n = n0 + j;
            if (n < N) {
                size_t off = (size_t)n * H + c;
                float2 hv = *(const float2*)&hN[off];
                float2 av = *(const float2*)&zb[off];
                float2 zv;
                zv.x = fmaf(e1, hv.x, av.x);
                zv.y = fmaf(e1, hv.y, av.y);
                *(float2*)&sB[w][j][c] = zv;
            }
        }
        __builtin_amdgcn_wave_barrier();

        float ax[4], ay[4];
#pragma unroll
        for (int j = 0; j < 4; ++j) { ax[j] = bb1.x; ay[j] = bb1.y; }
#pragma unroll 4
        for (int k0 = 0; k0 < H; k0 += 4) {
            float zv[4][4];
#pragma unroll
            for (int j = 0; j < 4; ++j) {
                float4 t = *(const float4*)&sB[w][j][k0];
                zv[j][0] = t.x; zv[j][1] = t.y; zv[j][2] = t.z; zv[j][3] = t.w;
            }
#pragma unroll
            for (int kk = 0; kk < 4; ++kk) {
                float2 wv = *(const float2*)&sW1[(k0 + kk) * H + c];
#pragma unroll
                for (int j = 0; j < 4; ++j) {
                    ax[j] = fmaf(zv[j][kk], wv.x, ax[j]);
                    ay[j] = fmaf(zv[j][kk], wv.y, ay[j]);
                }
            }
        }
#pragma unroll
        for (int j = 0; j < 4; ++j) {
            float2 yv;
            yv.x = fmaxf(ax[j], 0.f);
            yv.y = fmaxf(ay[j], 0.f);
            *(float2*)&sB[w][j][c] = yv;
        }
        __builtin_amdgcn_wave_barrier();

        float cx[4], cy[4];
#pragma unroll
        for (int j = 0; j < 4; ++j) { cx[j] = bb2.x; cy[j] = bb2.y; }
#pragma unroll 4
        for (int k0 = 0; k0 < H; k0 += 4) {
            float yv[4][4];
#pragma unroll
            for (int j = 0; j < 4; ++j) {
                float4 t = *(const float4*)&sB[w][j][k0];
                yv[j][0] = t.x; yv[j][1] = t.y; yv[j][2] = t.z; yv[j][3] = t.w;
            }
#pragma unroll
            for (int kk = 0; kk < 4; ++kk) {
                float2 wv = *(const float2*)&sW2[(k0 + kk) * H + c];
#pragma unroll
                for (int j = 0; j < 4; ++j) {
                    cx[j] = fmaf(yv[j][kk], wv.x, cx[j]);
                    cy[j] = fmaf(yv[j][kk], wv.y, cy[j]);
                }
            }
        }
        __builtin_amdgcn_wave_barrier();

#pragma unroll
        for (int j = 0; j < 4; ++j) {
            int n = n0 + j;
            if (n < N) {
                float z2x = fmaxf(cx[j], 0.f);
                float z2y = fmaxf(cy[j], 0.f);
                size_t off = (size_t)n * H + c;
                float2 o; o.x = z2x; o.y = z2y;
                *(float2*)&zb[off] = o;
                s0 += z2x; s1 += z2y;
                q0 += z2x * z2x; q1 += z2y * z2y;
            }
        }
    }

    __syncthreads();
    atomicAdd(&sRed[c],     s0);
    atomicAdd(&sRed[c + 1], s1);
    atomicAdd(&sRed[H + c],     q0);
    atomicAdd(&sRed[H + c + 1], q1);
    __syncthreads();
    if (tid < H) {
        atomicAdd(&g_stats[tid],     sRed[tid]);
        atomicAdd(&g_stats[H + tid], sRed[H + tid]);
    }
}

__global__ void k_bnfin(const float* __restrict__ gamma, const float* __restrict__ beta,
                        float invN)
{
    int t = threadIdx.x;
    float mean = g_stats[t] * invN;
    float var  = g_stats[H + t] * invN - mean * mean;
    float sc = gamma[t] * rsqrtf(var + 1e-5f);
    g_stats[256 + t] = sc;
    g_stats[384 + t] = beta[t] - mean * sc;
}

__global__ void k_final(const float* __restrict__ hN, const float* __restrict__ valid,
                        float* __restrict__ out, int N)
{
    const int total = N * (H / 4);
    for (int i = blockIdx.x * blockDim.x + threadIdx.x; i < total;
         i += gridDim.x * blockDim.x) {
        int col4 = i & 31;
        int n = i >> 5;
        float4 z = ((float4*)out)[i];
        float4 hv = ((const float4*)hN)[i];
        float4 sc = *(const float4*)&g_stats[256 + col4 * 4];
        float4 sh = *(const float4*)&g_stats[384 + col4 * 4];
        float vf = valid[n];
        float4 r;
        r.x = (hv.x + fmaf(z.x, sc.x, sh.x)) * vf;
        r.y = (hv.y + fmaf(z.y, sc.y, sh.y)) * vf;
        r.z = (hv.z + fmaf(z.z, sc.z, sh.z)) * vf;
        r.w = (hv.w + fmaf(z.w, sc.w, sh.w)) * vf;
        ((float4*)out)[i] = r;
    }
}

extern "C" void kernel_launch(void* const* d_in, const int* in_sizes, int n_in,
                              void* d_out, int out_size, void* d_ws, size_t ws_size,
                              hipStream_t stream) {
    const float* hN    = (const float*)d_in[0];
    const int*   ei    = (const int*)d_in[1];
    const float* ea    = (const float*)d_in[2];
    const float* valid = (const float*)d_in[3];
    const float* We    = (const float*)d_in[4];
    const float* be    = (const float*)d_in[5];
    const float* W1    = (const float*)d_in[6];
    const float* b1    = (const float*)d_in[7];
    const float* W2    = (const float*)d_in[8];
    const float* b2    = (const float*)d_in[9];
    const float* epsg  = (const float*)d_in[10];
    const float* gamma = (const float*)d_in[11];
    const float* beta  = (const float*)d_in[12];
    float* out = (float*)d_out;

    const int N = in_sizes[0] / H;
    const int E = in_sizes[1] / 2;

    // workspace layout: cnt[N] | off[N+1] | cur[N] | perm[E]
    const size_t need = ((size_t)N * 3 + 1 + (size_t)E) * sizeof(int);

    k_zero_stats<<<1, 512, 0, stream>>>();

    if (ws_size >= need) {
        int* cnt  = (int*)d_ws;
        int* off  = cnt + N;
        int* cur  = off + N + 1;
        int* perm = cur + N;
        hipMemsetAsync(cnt, 0, (size_t)N * sizeof(int), stream);
        k_hist<<<2048, 256, 0, stream>>>(ei, cnt, E);
        k_scan<<<1, 1024, 0, stream>>>(cnt, off, cur, N);
        k_fill<<<2048, 256, 0, stream>>>(ei, cur, perm, E);
        k_edge_g<<<2048, 256, 0, stream>>>(hN, ei, ea, We, be, off, perm, out, N, E);
    } else {
        hipMemsetAsync(d_out, 0, (size_t)out_size * sizeof(float), stream);
        k_edge<<<2048, 256, 0, stream>>>(hN, ei, ea, We, be, out, E);
    }

    k_mlp<<<512, 512, 0, stream>>>(hN, out, W1, b1, W2, b2, epsg, N);
    k_bnfin<<<1, 128, 0, stream>>>(gamma, beta, 1.0f / (float)N);
    k_final<<<2048, 256, 0, stream>>>(hN, valid, out, N);
}

// Round 3
// 1627.099 us; speedup vs baseline: 9.2563x; 9.2563x over previous
//
#include <hip/hip_runtime.h>

#define H 128
#define ED 64
#define EB 8

// stats layout: [0:128) colsum, [128:256) colsumsq, [256:384) scale, [384:512) shift
__device__ __align__(16) float g_stats[512];

__global__ void k_zero_stats() {
    if (threadIdx.x < 512) g_stats[threadIdx.x] = 0.f;
}

// ================= CSR build =================
__global__ void k_hist(const int* __restrict__ ei, int* __restrict__ cnt, int E) {
    for (int e = blockIdx.x * blockDim.x + threadIdx.x; e < E;
         e += gridDim.x * blockDim.x)
        atomicAdd(&cnt[ei[E + e]], 1);
}

__global__ __launch_bounds__(1024) void k_scan(
    const int* __restrict__ cnt, int* __restrict__ off, int* __restrict__ cur,
    int N)
{
    __shared__ int part[1024];
    const int t = threadIdx.x;
    const int chunk = (N + 1023) >> 10;
    const int lo = t * chunk, hi = min(lo + chunk, N);
    int s = 0;
    for (int i = lo; i < hi; ++i) s += cnt[i];
    part[t] = s;
    __syncthreads();
    for (int d = 1; d < 1024; d <<= 1) {
        int v = (t >= d) ? part[t - d] : 0;
        __syncthreads();
        part[t] += v;
        __syncthreads();
    }
    int excl = (t == 0) ? 0 : part[t - 1];
    for (int i = lo; i < hi; ++i) {
        off[i] = excl; cur[i] = excl;
        excl += cnt[i];
    }
    if (t == 1023) off[N] = part[1023];
}

__global__ void k_fill(const int* __restrict__ ei, int* __restrict__ cur,
                       int* __restrict__ perm, int E) {
    for (int e = blockIdx.x * blockDim.x + threadIdx.x; e < E;
         e += gridDim.x * blockDim.x) {
        int pos = atomicAdd(&cur[ei[E + e]], 1);
        perm[pos] = e;
    }
}

// ================= Edge gather kernel =================
// one wave per dst node: agg[d] = sum_e relu(h[src_e] + ea[e]@We + be)
// Register budget: e8[8] + ax[8] + ay[8] + wv[4](f2) + transient f4 + misc ~ 50 VGPR.
__global__ __launch_bounds__(256, 4) void k_edge_g(
    const float* __restrict__ hN, const int* __restrict__ ei,
    const float* __restrict__ ea, const float* __restrict__ We,
    const float* __restrict__ be,
    const int* __restrict__ off, const int* __restrict__ perm,
    float* __restrict__ agg, int N, int E)
{
    __shared__ __align__(16) float sW[ED * H];        // 32 KB
    __shared__ __align__(16) float sEA[4][EB][ED];    // 8 KB
    const int tid = threadIdx.x;
    for (int i = tid; i < (ED * H) / 4; i += 256)
        ((float4*)sW)[i] = ((const float4*)We)[i];
    __syncthreads();

    const int w = tid >> 6, lane = tid & 63;
    const int c = lane << 1;                          // columns {c, c+1}
    const float2 bb = *(const float2*)&be[c];
    const int waveId = (blockIdx.x << 2) | w;
    const int nWaves = gridDim.x << 2;

    for (int d = waveId; d < N; d += nWaves) {
        const int base = off[d], end = off[d + 1];
        float a0 = 0.f, a1 = 0.f;
        for (int e0 = base; e0 < end; e0 += EB) {
            const int m = end - e0;                   // valid edges this group
            int e8[EB];
#pragma unroll
            for (int j = 0; j < EB; ++j) {
                if (j < m) {
                    e8[j] = perm[e0 + j];
                    sEA[w][j][lane] = ea[(size_t)e8[j] * ED + lane];
                } else {
                    e8[j] = 0;
                }
            }
            __builtin_amdgcn_wave_barrier();

            float ax[EB], ay[EB];
#pragma unroll
            for (int j = 0; j < EB; ++j) { ax[j] = bb.x; ay[j] = bb.y; }

            // wv outer (shared over edges), edge inner with broadcast b128 reads.
#pragma unroll 4
            for (int k0 = 0; k0 < ED; k0 += 4) {
                const float2 wv0 = *(const float2*)&sW[(k0 + 0) * H + c];
                const float2 wv1 = *(const float2*)&sW[(k0 + 1) * H + c];
                const float2 wv2 = *(const float2*)&sW[(k0 + 2) * H + c];
                const float2 wv3 = *(const float2*)&sW[(k0 + 3) * H + c];
#pragma unroll
                for (int j = 0; j < EB; ++j) {
                    const float4 a = *(const float4*)&sEA[w][j][k0];
                    ax[j] = fmaf(a.x, wv0.x, ax[j]);
                    ay[j] = fmaf(a.x, wv0.y, ay[j]);
                    ax[j] = fmaf(a.y, wv1.x, ax[j]);
                    ay[j] = fmaf(a.y, wv1.y, ay[j]);
                    ax[j] = fmaf(a.z, wv2.x, ax[j]);
                    ay[j] = fmaf(a.z, wv2.y, ay[j]);
                    ax[j] = fmaf(a.w, wv3.x, ax[j]);
                    ay[j] = fmaf(a.w, wv3.y, ay[j]);
                }
            }

#pragma unroll
            for (int j = 0; j < EB; ++j) {
                if (j < m) {
                    int s = ei[e8[j]];
                    float2 hv = *(const float2*)&hN[(size_t)s * H + c];
                    a0 += fmaxf(ax[j] + hv.x, 0.f);
                    a1 += fmaxf(ay[j] + hv.y, 0.f);
                }
            }
            __builtin_amdgcn_wave_barrier();
        }
        float2 o; o.x = a0; o.y = a1;
        *(float2*)&agg[(size_t)d * H + c] = o;
    }
}

// ================= Node MLP kernel =================
// z2 = relu(relu(((1+eps)h + agg)@W1 + b1)@W2 + b2), in place on zb; BN col sums.
__global__ __launch_bounds__(512, 2) void k_mlp(
    const float* __restrict__ hN, float* __restrict__ zb,
    const float* __restrict__ W1, const float* __restrict__ b1,
    const float* __restrict__ W2, const float* __restrict__ b2,
    const float* __restrict__ epsp, int N)
{
    __shared__ __align__(16) float sW1[H * H];        // 64 KB
    __shared__ __align__(16) float sW2[H * H];        // 64 KB
    __shared__ __align__(16) float sB[8][4][H];       // 16 KB
    __shared__ float sRed[2 * H];                     // 1 KB
    const int tid = threadIdx.x;
    for (int i = tid; i < (H * H) / 4; i += 512) {
        ((float4*)sW1)[i] = ((const float4*)W1)[i];
        ((float4*)sW2)[i] = ((const float4*)W2)[i];
    }
    if (tid < 2 * H) sRed[tid] = 0.f;
    __syncthreads();

    const int w = tid >> 6, lane = tid & 63;
    const int c = lane << 1;
    const float e1 = 1.f + epsp[0];
    const float2 bb1 = *(const float2*)&b1[c];
    const float2 bb2 = *(const float2*)&b2[c];
    float s0 = 0.f, s1 = 0.f, q0 = 0.f, q1 = 0.f;

    const int waveId = (blockIdx.x << 3) | w;
    const int nWaves = gridDim.x << 3;
    const int nGroups = (N + 3) >> 2;

    for (int g = waveId; g < nGroups; g += nWaves) {
        const int n0 = g << 2;
#pragma unroll
        for (int j = 0; j < 4; ++j) {
            int n = n0 + j;
            if (n < N) {
                size_t o = (size_t)n * H + c;
                float2 hv = *(const float2*)&hN[o];
                float2 av = *(const float2*)&zb[o];
                float2 zv;
                zv.x = fmaf(e1, hv.x, av.x);
                zv.y = fmaf(e1, hv.y, av.y);
                *(float2*)&sB[w][j][c] = zv;
            }
        }
        __builtin_amdgcn_wave_barrier();

        // ---- layer 1: wv outer, node inner (broadcast reads of sB)
        float ax[4], ay[4];
#pragma unroll
        for (int j = 0; j < 4; ++j) { ax[j] = bb1.x; ay[j] = bb1.y; }
#pragma unroll 4
        for (int k0 = 0; k0 < H; k0 += 4) {
            const float2 wv0 = *(const float2*)&sW1[(k0 + 0) * H + c];
            const float2 wv1 = *(const float2*)&sW1[(k0 + 1) * H + c];
            const float2 wv2 = *(const float2*)&sW1[(k0 + 2) * H + c];
            const float2 wv3 = *(const float2*)&sW1[(k0 + 3) * H + c];
#pragma unroll
            for (int j = 0; j < 4; ++j) {
                const float4 a = *(const float4*)&sB[w][j][k0];
                ax[j] = fmaf(a.x, wv0.x, ax[j]);
                ay[j] = fmaf(a.x, wv0.y, ay[j]);
                ax[j] = fmaf(a.y, wv1.x, ax[j]);
                ay[j] = fmaf(a.y, wv1.y, ay[j]);
                ax[j] = fmaf(a.z, wv2.x, ax[j]);
                ay[j] = fmaf(a.z, wv2.y, ay[j]);
                ax[j] = fmaf(a.w, wv3.x, ax[j]);
                ay[j] = fmaf(a.w, wv3.y, ay[j]);
            }
        }
#pragma unroll
        for (int j = 0; j < 4; ++j) {
            float2 yv;
            yv.x = fmaxf(ax[j], 0.f);
            yv.y = fmaxf(ay[j], 0.f);
            *(float2*)&sB[w][j][c] = yv;
        }
        __builtin_amdgcn_wave_barrier();

        // ---- layer 2
        float cx[4], cy[4];
#pragma unroll
        for (int j = 0; j < 4; ++j) { cx[j] = bb2.x; cy[j] = bb2.y; }
#pragma unroll 4
        for (int k0 = 0; k0 < H; k0 += 4) {
            const float2 wv0 = *(const float2*)&sW2[(k0 + 0) * H + c];
            const float2 wv1 = *(const float2*)&sW2[(k0 + 1) * H + c];
            const float2 wv2 = *(const float2*)&sW2[(k0 + 2) * H + c];
            const float2 wv3 = *(const float2*)&sW2[(k0 + 3) * H + c];
#pragma unroll
            for (int j = 0; j < 4; ++j) {
                const float4 a = *(const float4*)&sB[w][j][k0];
                cx[j] = fmaf(a.x, wv0.x, cx[j]);
                cy[j] = fmaf(a.x, wv0.y, cy[j]);
                cx[j] = fmaf(a.y, wv1.x, cx[j]);
                cy[j] = fmaf(a.y, wv1.y, cy[j]);
                cx[j] = fmaf(a.z, wv2.x, cx[j]);
                cy[j] = fmaf(a.z, wv2.y, cy[j]);
                cx[j] = fmaf(a.w, wv3.x, cx[j]);
                cy[j] = fmaf(a.w, wv3.y, cy[j]);
            }
        }
        __builtin_amdgcn_wave_barrier();

#pragma unroll
        for (int j = 0; j < 4; ++j) {
            int n = n0 + j;
            if (n < N) {
                float z2x = fmaxf(cx[j], 0.f);
                float z2y = fmaxf(cy[j], 0.f);
                size_t o = (size_t)n * H + c;
                float2 ov; ov.x = z2x; ov.y = z2y;
                *(float2*)&zb[o] = ov;
                s0 += z2x; s1 += z2y;
                q0 += z2x * z2x; q1 += z2y * z2y;
            }
        }
    }

    __syncthreads();
    atomicAdd(&sRed[c],     s0);
    atomicAdd(&sRed[c + 1], s1);
    atomicAdd(&sRed[H + c],     q0);
    atomicAdd(&sRed[H + c + 1], q1);
    __syncthreads();
    if (tid < H) {
        atomicAdd(&g_stats[tid],     sRed[tid]);
        atomicAdd(&g_stats[H + tid], sRed[H + tid]);
    }
}

__global__ void k_bnfin(const float* __restrict__ gamma, const float* __restrict__ beta,
                        float invN)
{
    int t = threadIdx.x;
    float mean = g_stats[t] * invN;
    float var  = g_stats[H + t] * invN - mean * mean;
    float sc = gamma[t] * rsqrtf(var + 1e-5f);
    g_stats[256 + t] = sc;
    g_stats[384 + t] = beta[t] - mean * sc;
}

__global__ void k_final(const float* __restrict__ hN, const float* __restrict__ valid,
                        float* __restrict__ out, int N)
{
    const int total = N * (H / 4);
    for (int i = blockIdx.x * blockDim.x + threadIdx.x; i < total;
         i += gridDim.x * blockDim.x) {
        int col4 = i & 31;
        int n = i >> 5;
        float4 z = ((float4*)out)[i];
        float4 hv = ((const float4*)hN)[i];
        float4 sc = *(const float4*)&g_stats[256 + col4 * 4];
        float4 sh = *(const float4*)&g_stats[384 + col4 * 4];
        float vf = valid[n];
        float4 r;
        r.x = (hv.x + fmaf(z.x, sc.x, sh.x)) * vf;
        r.y = (hv.y + fmaf(z.y, sc.y, sh.y)) * vf;
        r.z = (hv.z + fmaf(z.z, sc.z, sh.z)) * vf;
        r.w = (hv.w + fmaf(z.w, sc.w, sh.w)) * vf;
        ((float4*)out)[i] = r;
    }
}

// ================= Fallback (ws too small): atomic edge kernel, low-pressure =================
__global__ __launch_bounds__(256, 4) void k_edge(
    const float* __restrict__ hN, const int* __restrict__ ei,
    const float* __restrict__ ea, const float* __restrict__ We,
    const float* __restrict__ be, float* __restrict__ agg, int E)
{
    __shared__ __align__(16) float sW[ED * H];
    __shared__ __align__(16) float sEA[4][4][ED];
    const int tid = threadIdx.x;
    for (int i = tid; i < (ED * H) / 4; i += 256)
        ((float4*)sW)[i] = ((const float4*)We)[i];
    __syncthreads();
    const int w = tid >> 6, lane = tid & 63;
    const int c = lane << 1;
    const float2 bb = *(const float2*)&be[c];
    const int waveId = (blockIdx.x << 2) | w;
    const int nWaves = gridDim.x << 2;
    const int nGroups = (E + 3) >> 2;
    for (int g = waveId; g < nGroups; g += nWaves) {
        const int e0 = g << 2;
#pragma unroll
        for (int j = 0; j < 4; ++j) {
            int e = e0 + j;
            if (e < E) sEA[w][j][lane] = ea[(size_t)e * ED + lane];
        }
        __builtin_amdgcn_wave_barrier();
        float ax[4], ay[4];
#pragma unroll
        for (int j = 0; j < 4; ++j) { ax[j] = bb.x; ay[j] = bb.y; }
#pragma unroll 4
        for (int k0 = 0; k0 < ED; k0 += 4) {
            const float2 wv0 = *(const float2*)&sW[(k0 + 0) * H + c];
            const float2 wv1 = *(const float2*)&sW[(k0 + 1) * H + c];
            const float2 wv2 = *(const float2*)&sW[(k0 + 2) * H + c];
            const float2 wv3 = *(const float2*)&sW[(k0 + 3) * H + c];
#pragma unroll
            for (int j = 0; j < 4; ++j) {
                const float4 a = *(const float4*)&sEA[w][j][k0];
                ax[j] = fmaf(a.x, wv0.x, ax[j]);
                ay[j] = fmaf(a.x, wv0.y, ay[j]);
                ax[j] = fmaf(a.y, wv1.x, ax[j]);
                ay[j] = fmaf(a.y, wv1.y, ay[j]);
                ax[j] = fmaf(a.z, wv2.x, ax[j]);
                ay[j] = fmaf(a.z, wv2.y, ay[j]);
                ax[j] = fmaf(a.w, wv3.x, ax[j]);
                ay[j] = fmaf(a.w, wv3.y, ay[j]);
            }
        }
#pragma unroll
        for (int j = 0; j < 4; ++j) {
            int e = e0 + j;
            if (e < E) {
                int s = ei[e];
                int d = ei[E + e];
                float2 hv = *(const float2*)&hN[(size_t)s * H + c];
                atomicAdd(&agg[(size_t)d * H + c],     fmaxf(ax[j] + hv.x, 0.f));
                atomicAdd(&agg[(size_t)d * H + c + 1], fmaxf(ay[j] + hv.y, 0.f));
            }
        }
        __builtin_amdgcn_wave_barrier();
    }
}

extern "C" void kernel_launch(void* const* d_in, const int* in_sizes, int n_in,
                              void* d_out, int out_size, void* d_ws, size_t ws_size,
                              hipStream_t stream) {
    const float* hN    = (const float*)d_in[0];
    const int*   ei    = (const int*)d_in[1];
    const float* ea    = (const float*)d_in[2];
    const float* valid = (const float*)d_in[3];
    const float* We    = (const float*)d_in[4];
    const float* be    = (const float*)d_in[5];
    const float* W1    = (const float*)d_in[6];
    const float* b1    = (const float*)d_in[7];
    const float* W2    = (const float*)d_in[8];
    const float* b2    = (const float*)d_in[9];
    const float* epsg  = (const float*)d_in[10];
    const float* gamma = (const float*)d_in[11];
    const float* beta  = (const float*)d_in[12];
    float* out = (float*)d_out;

    const int N = in_sizes[0] / H;
    const int E = in_sizes[1] / 2;

    // workspace layout: cnt[N] | off[N+1] | cur[N] | perm[E]
    const size_t need = ((size_t)N * 3 + 1 + (size_t)E) * sizeof(int);

    k_zero_stats<<<1, 512, 0, stream>>>();

    if (ws_size >= need) {
        int* cnt  = (int*)d_ws;
        int* off  = cnt + N;
        int* cur  = off + N + 1;
        int* perm = cur + N;
        hipMemsetAsync(cnt, 0, (size_t)N * sizeof(int), stream);
        k_hist<<<2048, 256, 0, stream>>>(ei, cnt, E);
        k_scan<<<1, 1024, 0, stream>>>(cnt, off, cur, N);
        k_fill<<<2048, 256, 0, stream>>>(ei, cur, perm, E);
        k_edge_g<<<2048, 256, 0, stream>>>(hN, ei, ea, We, be, off, perm, out, N, E);
    } else {
        hipMemsetAsync(d_out, 0, (size_t)out_size * sizeof(float), stream);
        k_edge<<<2048, 256, 0, stream>>>(hN, ei, ea, We, be, out, E);
    }

    k_mlp<<<512, 512, 0, stream>>>(hN, out, W1, b1, W2, b2, epsg, N);
    k_bnfin<<<1, 128, 0, stream>>>(gamma, beta, 1.0f / (float)N);
    k_final<<<2048, 256, 0, stream>>>(hN, valid, out, N);
}

// Round 4
// 1216.839 us; speedup vs baseline: 12.3770x; 1.3372x over previous
//
#include <hip/hip_runtime.h>

#define H 128
#define ED 64
#define EB 8

// stats layout: [0:128) colsum, [128:256) colsumsq, [256:384) scale, [384:512) shift
__device__ __align__(16) float g_stats[512];

__global__ void k_zero_stats() {
    if (threadIdx.x < 512) g_stats[threadIdx.x] = 0.f;
}

// ================= CSR build =================
__global__ void k_hist(const int* __restrict__ ei, int* __restrict__ cnt, int E) {
    for (int e = blockIdx.x * blockDim.x + threadIdx.x; e < E;
         e += gridDim.x * blockDim.x)
        atomicAdd(&cnt[ei[E + e]], 1);
}

__global__ __launch_bounds__(1024) void k_scan(
    const int* __restrict__ cnt, int* __restrict__ off, int* __restrict__ cur,
    int N)
{
    __shared__ int part[1024];
    const int t = threadIdx.x;
    const int chunk = (N + 1023) >> 10;
    const int lo = t * chunk, hi = min(lo + chunk, N);
    int s = 0;
    for (int i = lo; i < hi; ++i) s += cnt[i];
    part[t] = s;
    __syncthreads();
    for (int d = 1; d < 1024; d <<= 1) {
        int v = (t >= d) ? part[t - d] : 0;
        __syncthreads();
        part[t] += v;
        __syncthreads();
    }
    int excl = (t == 0) ? 0 : part[t - 1];
    for (int i = lo; i < hi; ++i) {
        off[i] = excl; cur[i] = excl;
        excl += cnt[i];
    }
    if (t == 1023) off[N] = part[1023];
}

__global__ void k_fill(const int* __restrict__ ei, int* __restrict__ cur,
                       int* __restrict__ perm, int E) {
    for (int e = blockIdx.x * blockDim.x + threadIdx.x; e < E;
         e += gridDim.x * blockDim.x) {
        int pos = atomicAdd(&cur[ei[E + e]], 1);
        perm[pos] = e;
    }
}

// ================= Edge gather kernel (software-pipelined) =================
// one wave per dst node: agg[d] = sum_e relu(h[src_e] + ea[e]@We + be)
__global__ __launch_bounds__(256, 3) void k_edge_g(
    const float* __restrict__ hN, const int* __restrict__ ei,
    const float* __restrict__ ea, const float* __restrict__ We,
    const float* __restrict__ be,
    const int* __restrict__ off, const int* __restrict__ perm,
    float* __restrict__ agg, int N, int E)
{
    __shared__ __align__(16) float sW[ED * H];           // 32 KB
    __shared__ __align__(16) float sEA[2][4][EB][ED];    // 16 KB (dbuf, wave, edge, k)
    const int tid = threadIdx.x;
    for (int i = tid; i < (ED * H) / 4; i += 256)
        ((float4*)sW)[i] = ((const float4*)We)[i];
    __syncthreads();

    const int w = tid >> 6, lane = tid & 63;
    const int c = lane << 1;                             // columns {c, c+1}
    const float2 bb = *(const float2*)&be[c];
    const int waveId = (blockIdx.x << 2) | w;
    const int nWaves = gridDim.x << 2;

    for (int d = waveId; d < N; d += nWaves) {
        const int base = off[d], end = off[d + 1];
        float a0 = 0.f, a1 = 0.f;
        const int nE = end - base;
        if (nE > 0) {
            int e8[EB]; float ear[EB]; int src[EB];
            // prologue prefetch: group 0
            {
                const int m = min(nE, EB);
#pragma unroll
                for (int j = 0; j < EB; ++j) {
                    int p = base + ((j < m) ? j : (m - 1));
                    e8[j] = perm[p];
                }
#pragma unroll
                for (int j = 0; j < EB; ++j)
                    ear[j] = ea[(size_t)e8[j] * ED + lane];
#pragma unroll
                for (int j = 0; j < EB; ++j)
                    src[j] = ei[e8[j]];
            }
            int buf = 0;
            for (int e0 = base; e0 < end; e0 += EB) {
                const int m = min(end - e0, EB);
                // 1) write staged ea regs for CURRENT group to LDS
#pragma unroll
                for (int j = 0; j < EB; ++j)
                    sEA[buf][w][j][lane] = ear[j];
                // 2) issue h gathers for CURRENT group (consumed in epilogue)
                float2 hv[EB];
#pragma unroll
                for (int j = 0; j < EB; ++j)
                    hv[j] = *(const float2*)&hN[(size_t)src[j] * H + c];
                // 3) prefetch NEXT group (perm -> ea regs, ei)
                const int e0n = e0 + EB;
                if (e0n < end) {
                    const int mn = min(end - e0n, EB);
#pragma unroll
                    for (int j = 0; j < EB; ++j) {
                        int p = e0n + ((j < mn) ? j : (mn - 1));
                        e8[j] = perm[p];
                    }
#pragma unroll
                    for (int j = 0; j < EB; ++j)
                        ear[j] = ea[(size_t)e8[j] * ED + lane];
#pragma unroll
                    for (int j = 0; j < EB; ++j)
                        src[j] = ei[e8[j]];
                }
                __builtin_amdgcn_wave_barrier();

                // 4) GEMV on sEA[buf]
                float ax[EB], ay[EB];
#pragma unroll
                for (int j = 0; j < EB; ++j) { ax[j] = bb.x; ay[j] = bb.y; }
#pragma unroll 4
                for (int k0 = 0; k0 < ED; k0 += 4) {
                    const float2 wv0 = *(const float2*)&sW[(k0 + 0) * H + c];
                    const float2 wv1 = *(const float2*)&sW[(k0 + 1) * H + c];
                    const float2 wv2 = *(const float2*)&sW[(k0 + 2) * H + c];
                    const float2 wv3 = *(const float2*)&sW[(k0 + 3) * H + c];
#pragma unroll
                    for (int j = 0; j < EB; ++j) {
                        const float4 a = *(const float4*)&sEA[buf][w][j][k0];
                        ax[j] = fmaf(a.x, wv0.x, ax[j]);
                        ay[j] = fmaf(a.x, wv0.y, ay[j]);
                        ax[j] = fmaf(a.y, wv1.x, ax[j]);
                        ay[j] = fmaf(a.y, wv1.y, ay[j]);
                        ax[j] = fmaf(a.z, wv2.x, ax[j]);
                        ay[j] = fmaf(a.z, wv2.y, ay[j]);
                        ax[j] = fmaf(a.w, wv3.x, ax[j]);
                        ay[j] = fmaf(a.w, wv3.y, ay[j]);
                    }
                }
                // 5) epilogue: relu(msg + h[src]) accumulate (hv latency hidden by GEMV)
#pragma unroll
                for (int j = 0; j < EB; ++j) {
                    if (j < m) {
                        a0 += fmaxf(ax[j] + hv[j].x, 0.f);
                        a1 += fmaxf(ay[j] + hv[j].y, 0.f);
                    }
                }
                buf ^= 1;
                __builtin_amdgcn_wave_barrier();
            }
        }
        float2 o; o.x = a0; o.y = a1;
        *(float2*)&agg[(size_t)d * H + c] = o;
    }
}

// ================= Node MLP kernel (pipelined loads) =================
__global__ __launch_bounds__(512, 2) void k_mlp(
    const float* __restrict__ hN, float* __restrict__ zb,
    const float* __restrict__ W1, const float* __restrict__ b1,
    const float* __restrict__ W2, const float* __restrict__ b2,
    const float* __restrict__ epsp, int N)
{
    __shared__ __align__(16) float sW1[H * H];           // 64 KB
    __shared__ __align__(16) float sW2[H * H];           // 64 KB
    __shared__ __align__(16) float sB[8][4][H];          // 16 KB
    __shared__ float sRed[2 * H];                        // 1 KB
    const int tid = threadIdx.x;
    for (int i = tid; i < (H * H) / 4; i += 512) {
        ((float4*)sW1)[i] = ((const float4*)W1)[i];
        ((float4*)sW2)[i] = ((const float4*)W2)[i];
    }
    if (tid < 2 * H) sRed[tid] = 0.f;
    __syncthreads();

    const int w = tid >> 6, lane = tid & 63;
    const int c = lane << 1;
    const float e1 = 1.f + epsp[0];
    const float2 bb1 = *(const float2*)&b1[c];
    const float2 bb2 = *(const float2*)&b2[c];
    float s0 = 0.f, s1 = 0.f, q0 = 0.f, q1 = 0.f;

    const int waveId = (blockIdx.x << 3) | w;
    const int nWaves = gridDim.x << 3;
    const int nGroups = (N + 3) >> 2;

    float2 hvp[4], avp[4];
    int g0 = waveId;
    if (g0 < nGroups) {
#pragma unroll
        for (int j = 0; j < 4; ++j) {
            int n = min(4 * g0 + j, N - 1);
            size_t o = (size_t)n * H + c;
            hvp[j] = *(const float2*)&hN[o];
            avp[j] = *(const float2*)&zb[o];
        }
    }

    for (int g = g0; g < nGroups; g += nWaves) {
        const int n0 = g << 2;
        // 1) combine prefetched h/agg -> z, stage to LDS
#pragma unroll
        for (int j = 0; j < 4; ++j) {
            float2 zv;
            zv.x = fmaf(e1, hvp[j].x, avp[j].x);
            zv.y = fmaf(e1, hvp[j].y, avp[j].y);
            *(float2*)&sB[w][j][c] = zv;
        }
        // 2) prefetch NEXT group's h/agg (latency hides under both GEMVs)
        const int gn = g + nWaves;
        if (gn < nGroups) {
#pragma unroll
            for (int j = 0; j < 4; ++j) {
                int n = min(4 * gn + j, N - 1);
                size_t o = (size_t)n * H + c;
                hvp[j] = *(const float2*)&hN[o];
                avp[j] = *(const float2*)&zb[o];
            }
        }
        __builtin_amdgcn_wave_barrier();

        // ---- layer 1
        float ax[4], ay[4];
#pragma unroll
        for (int j = 0; j < 4; ++j) { ax[j] = bb1.x; ay[j] = bb1.y; }
#pragma unroll 4
        for (int k0 = 0; k0 < H; k0 += 4) {
            const float2 wv0 = *(const float2*)&sW1[(k0 + 0) * H + c];
            const float2 wv1 = *(const float2*)&sW1[(k0 + 1) * H + c];
            const float2 wv2 = *(const float2*)&sW1[(k0 + 2) * H + c];
            const float2 wv3 = *(const float2*)&sW1[(k0 + 3) * H + c];
#pragma unroll
            for (int j = 0; j < 4; ++j) {
                const float4 a = *(const float4*)&sB[w][j][k0];
                ax[j] = fmaf(a.x, wv0.x, ax[j]);
                ay[j] = fmaf(a.x, wv0.y, ay[j]);
                ax[j] = fmaf(a.y, wv1.x, ax[j]);
                ay[j] = fmaf(a.y, wv1.y, ay[j]);
                ax[j] = fmaf(a.z, wv2.x, ax[j]);
                ay[j] = fmaf(a.z, wv2.y, ay[j]);
                ax[j] = fmaf(a.w, wv3.x, ax[j]);
                ay[j] = fmaf(a.w, wv3.y, ay[j]);
            }
        }
#pragma unroll
        for (int j = 0; j < 4; ++j) {
            float2 yv;
            yv.x = fmaxf(ax[j], 0.f);
            yv.y = fmaxf(ay[j], 0.f);
            *(float2*)&sB[w][j][c] = yv;
        }
        __builtin_amdgcn_wave_barrier();

        // ---- layer 2
        float cx[4], cy[4];
#pragma unroll
        for (int j = 0; j < 4; ++j) { cx[j] = bb2.x; cy[j] = bb2.y; }
#pragma unroll 4
        for (int k0 = 0; k0 < H; k0 += 4) {
            const float2 wv0 = *(const float2*)&sW2[(k0 + 0) * H + c];
            const float2 wv1 = *(const float2*)&sW2[(k0 + 1) * H + c];
            const float2 wv2 = *(const float2*)&sW2[(k0 + 2) * H + c];
            const float2 wv3 = *(const float2*)&sW2[(k0 + 3) * H + c];
#pragma unroll
            for (int j = 0; j < 4; ++j) {
                const float4 a = *(const float4*)&sB[w][j][k0];
                cx[j] = fmaf(a.x, wv0.x, cx[j]);
                cy[j] = fmaf(a.x, wv0.y, cy[j]);
                cx[j] = fmaf(a.y, wv1.x, cx[j]);
                cy[j] = fmaf(a.y, wv1.y, cy[j]);
                cx[j] = fmaf(a.z, wv2.x, cx[j]);
                cy[j] = fmaf(a.z, wv2.y, cy[j]);
                cx[j] = fmaf(a.w, wv3.x, cx[j]);
                cy[j] = fmaf(a.w, wv3.y, cy[j]);
            }
        }
        __builtin_amdgcn_wave_barrier();

#pragma unroll
        for (int j = 0; j < 4; ++j) {
            int n = n0 + j;
            if (n < N) {
                float z2x = fmaxf(cx[j], 0.f);
                float z2y = fmaxf(cy[j], 0.f);
                size_t o = (size_t)n * H + c;
                float2 ov; ov.x = z2x; ov.y = z2y;
                *(float2*)&zb[o] = ov;
                s0 += z2x; s1 += z2y;
                q0 += z2x * z2x; q1 += z2y * z2y;
            }
        }
        __builtin_amdgcn_wave_barrier();
    }

    __syncthreads();
    atomicAdd(&sRed[c],     s0);
    atomicAdd(&sRed[c + 1], s1);
    atomicAdd(&sRed[H + c],     q0);
    atomicAdd(&sRed[H + c + 1], q1);
    __syncthreads();
    if (tid < H) {
        atomicAdd(&g_stats[tid],     sRed[tid]);
        atomicAdd(&g_stats[H + tid], sRed[H + tid]);
    }
}

__global__ void k_bnfin(const float* __restrict__ gamma, const float* __restrict__ beta,
                        float invN)
{
    int t = threadIdx.x;
    float mean = g_stats[t] * invN;
    float var  = g_stats[H + t] * invN - mean * mean;
    float sc = gamma[t] * rsqrtf(var + 1e-5f);
    g_stats[256 + t] = sc;
    g_stats[384 + t] = beta[t] - mean * sc;
}

__global__ void k_final(const float* __restrict__ hN, const float* __restrict__ valid,
                        float* __restrict__ out, int N)
{
    const int total = N * (H / 4);
    for (int i = blockIdx.x * blockDim.x + threadIdx.x; i < total;
         i += gridDim.x * blockDim.x) {
        int col4 = i & 31;
        int n = i >> 5;
        float4 z = ((float4*)out)[i];
        float4 hv = ((const float4*)hN)[i];
        float4 sc = *(const float4*)&g_stats[256 + col4 * 4];
        float4 sh = *(const float4*)&g_stats[384 + col4 * 4];
        float vf = valid[n];
        float4 r;
        r.x = (hv.x + fmaf(z.x, sc.x, sh.x)) * vf;
        r.y = (hv.y + fmaf(z.y, sc.y, sh.y)) * vf;
        r.z = (hv.z + fmaf(z.z, sc.z, sh.z)) * vf;
        r.w = (hv.w + fmaf(z.w, sc.w, sh.w)) * vf;
        ((float4*)out)[i] = r;
    }
}

// ================= Fallback (ws too small): atomic edge kernel =================
__global__ __launch_bounds__(256, 4) void k_edge(
    const float* __restrict__ hN, const int* __restrict__ ei,
    const float* __restrict__ ea, const float* __restrict__ We,
    const float* __restrict__ be, float* __restrict__ agg, int E)
{
    __shared__ __align__(16) float sW[ED * H];
    __shared__ __align__(16) float sEA[4][4][ED];
    const int tid = threadIdx.x;
    for (int i = tid; i < (ED * H) / 4; i += 256)
        ((float4*)sW)[i] = ((const float4*)We)[i];
    __syncthreads();
    const int w = tid >> 6, lane = tid & 63;
    const int c = lane << 1;
    const float2 bb = *(const float2*)&be[c];
    const int waveId = (blockIdx.x << 2) | w;
    const int nWaves = gridDim.x << 2;
    const int nGroups = (E + 3) >> 2;
    for (int g = waveId; g < nGroups; g += nWaves) {
        const int e0 = g << 2;
#pragma unroll
        for (int j = 0; j < 4; ++j) {
            int e = e0 + j;
            if (e < E) sEA[w][j][lane] = ea[(size_t)e * ED + lane];
        }
        __builtin_amdgcn_wave_barrier();
        float ax[4], ay[4];
#pragma unroll
        for (int j = 0; j < 4; ++j) { ax[j] = bb.x; ay[j] = bb.y; }
#pragma unroll 4
        for (int k0 = 0; k0 < ED; k0 += 4) {
            const float2 wv0 = *(const float2*)&sW[(k0 + 0) * H + c];
            const float2 wv1 = *(const float2*)&sW[(k0 + 1) * H + c];
            const float2 wv2 = *(const float2*)&sW[(k0 + 2) * H + c];
            const float2 wv3 = *(const float2*)&sW[(k0 + 3) * H + c];
#pragma unroll
            for (int j = 0; j < 4; ++j) {
                const float4 a = *(const float4*)&sEA[w][j][k0];
                ax[j] = fmaf(a.x, wv0.x, ax[j]);
                ay[j] = fmaf(a.x, wv0.y, ay[j]);
                ax[j] = fmaf(a.y, wv1.x, ax[j]);
                ay[j] = fmaf(a.y, wv1.y, ay[j]);
                ax[j] = fmaf(a.z, wv2.x, ax[j]);
                ay[j] = fmaf(a.z, wv2.y, ay[j]);
                ax[j] = fmaf(a.w, wv3.x, ax[j]);
                ay[j] = fmaf(a.w, wv3.y, ay[j]);
            }
        }
#pragma unroll
        for (int j = 0; j < 4; ++j) {
            int e = e0 + j;
            if (e < E) {
                int s = ei[e];
                int d = ei[E + e];
                float2 hv = *(const float2*)&hN[(size_t)s * H + c];
                atomicAdd(&agg[(size_t)d * H + c],     fmaxf(ax[j] + hv.x, 0.f));
                atomicAdd(&agg[(size_t)d * H + c + 1], fmaxf(ay[j] + hv.y, 0.f));
            }
        }
        __builtin_amdgcn_wave_barrier();
    }
}

extern "C" void kernel_launch(void* const* d_in, const int* in_sizes, int n_in,
                              void* d_out, int out_size, void* d_ws, size_t ws_size,
                              hipStream_t stream) {
    const float* hN    = (const float*)d_in[0];
    const int*   ei    = (const int*)d_in[1];
    const float* ea    = (const float*)d_in[2];
    const float* valid = (const float*)d_in[3];
    const float* We    = (const float*)d_in[4];
    const float* be    = (const float*)d_in[5];
    const float* W1    = (const float*)d_in[6];
    const float* b1    = (const float*)d_in[7];
    const float* W2    = (const float*)d_in[8];
    const float* b2    = (const float*)d_in[9];
    const float* epsg  = (const float*)d_in[10];
    const float* gamma = (const float*)d_in[11];
    const float* beta  = (const float*)d_in[12];
    float* out = (float*)d_out;

    const int N = in_sizes[0] / H;
    const int E = in_sizes[1] / 2;

    // workspace layout: cnt[N] | off[N+1] | cur[N] | perm[E]
    const size_t need = ((size_t)N * 3 + 1 + (size_t)E) * sizeof(int);

    k_zero_stats<<<1, 512, 0, stream>>>();

    if (ws_size >= need) {
        int* cnt  = (int*)d_ws;
        int* off  = cnt + N;
        int* cur  = off + N + 1;
        int* perm = cur + N;
        hipMemsetAsync(cnt, 0, (size_t)N * sizeof(int), stream);
        k_hist<<<2048, 256, 0, stream>>>(ei, cnt, E);
        k_scan<<<1, 1024, 0, stream>>>(cnt, off, cur, N);
        k_fill<<<2048, 256, 0, stream>>>(ei, cur, perm, E);
        k_edge_g<<<2048, 256, 0, stream>>>(hN, ei, ea, We, be, off, perm, out, N, E);
    } else {
        hipMemsetAsync(d_out, 0, (size_t)out_size * sizeof(float), stream);
        k_edge<<<2048, 256, 0, stream>>>(hN, ei, ea, We, be, out, E);
    }

    k_mlp<<<512, 512, 0, stream>>>(hN, out, W1, b1, W2, b2, epsg, N);
    k_bnfin<<<1, 128, 0, stream>>>(gamma, beta, 1.0f / (float)N);
    k_final<<<2048, 256, 0, stream>>>(hN, valid, out, N);
}

// Round 5
// 835.791 us; speedup vs baseline: 18.0199x; 1.4559x over previous
//
#include <hip/hip_runtime.h>

#define H 128
#define ED 64
#define CH 16   // edges per MFMA chunk

typedef __attribute__((ext_vector_type(8))) short short8;
typedef __attribute__((ext_vector_type(4))) float f32x4;

__device__ __align__(16) float g_stats[512];

__device__ __forceinline__ unsigned short f2bf(float f) {
    unsigned u = __float_as_uint(f);
    unsigned r = u + 0x7fffu + ((u >> 16) & 1u);   // RNE
    return (unsigned short)(r >> 16);
}

__global__ void k_zero_stats() {
    if (threadIdx.x < 512) g_stats[threadIdx.x] = 0.f;
}

// ================= CSR build =================
__global__ void k_hist(const int* __restrict__ ei, int* __restrict__ cnt, int E) {
    for (int e = blockIdx.x * blockDim.x + threadIdx.x; e < E;
         e += gridDim.x * blockDim.x)
        atomicAdd(&cnt[ei[E + e]], 1);
}

__global__ __launch_bounds__(1024) void k_scan(
    const int* __restrict__ cnt, int* __restrict__ off, int* __restrict__ cur,
    int N)
{
    __shared__ int part[1024];
    const int t = threadIdx.x;
    const int chunk = (N + 1023) >> 10;
    const int lo = t * chunk, hi = min(lo + chunk, N);
    int s = 0;
    for (int i = lo; i < hi; ++i) s += cnt[i];
    part[t] = s;
    __syncthreads();
    for (int d = 1; d < 1024; d <<= 1) {
        int v = (t >= d) ? part[t - d] : 0;
        __syncthreads();
        part[t] += v;
        __syncthreads();
    }
    int excl = (t == 0) ? 0 : part[t - 1];
    for (int i = lo; i < hi; ++i) {
        off[i] = excl; cur[i] = excl;
        excl += cnt[i];
    }
    if (t == 1023) off[N] = part[1023];
}

__global__ void k_fill(const int* __restrict__ ei, int* __restrict__ cur,
                       int* __restrict__ perm, int E) {
    for (int e = blockIdx.x * blockDim.x + threadIdx.x; e < E;
         e += gridDim.x * blockDim.x) {
        int pos = atomicAdd(&cur[ei[E + e]], 1);
        perm[pos] = e;
    }
}

// ================= MFMA edge gather kernel =================
// wave per dst node; chunks of 16 edges; D = ea_tile[16x64] @ We[64x128] via
// 8 col-tiles x 2 K-steps of mfma_f32_16x16x32_bf16.
// A lane mapping: row = lane&15, k = 8*(lane>>4)+b (+32 per K-step)
// C/D lane mapping (guide-verified): col = lane&15, row = 4*(lane>>4)+reg
__global__ __launch_bounds__(256, 3) void k_edge_m(
    const float* __restrict__ hN, const int* __restrict__ ei,
    const float* __restrict__ ea, const float* __restrict__ We,
    const float* __restrict__ be,
    const int* __restrict__ off, const int* __restrict__ perm,
    float* __restrict__ agg, int N, int E)
{
    __shared__ unsigned sWb[ED * H / 2];                 // 16 KB bf16-packed We
    __shared__ __align__(16) short sBf[8][2][64][8];     // 16 KB B-fragments
    __shared__ int sPerm[4][2][CH];
    __shared__ int sSrc[4][2][CH];

    const int tid = threadIdx.x;
    // stage We as packed bf16 pairs (coalesced)
    for (int i = tid; i < ED * H / 2; i += 256) {
        float2 wv = ((const float2*)We)[i];
        sWb[i] = ((unsigned)f2bf(wv.y) << 16) | (unsigned)f2bf(wv.x);
    }
    __syncthreads();

    const int w = tid >> 6, l = tid & 63;
    const int rA = l & 15;        // A-row / D-col index
    const int kg = l >> 4;        // k-group / D-row-group

    // build per-lane B fragments once (wave 0 writes; values depend only on lane)
    if (w == 0) {
#pragma unroll
        for (int t = 0; t < 8; ++t)
#pragma unroll
            for (int s = 0; s < 2; ++s) {
                short8 f;
#pragma unroll
                for (int b = 0; b < 8; ++b) {
                    int k = (s << 5) + (kg << 3) + b;
                    f[b] = ((const short*)sWb)[k * H + (t << 4) + rA];
                }
                *(short8*)&sBf[t][s][l][0] = f;
            }
    }
    float beT[8];
#pragma unroll
    for (int t = 0; t < 8; ++t) beT[t] = be[(t << 4) + rA];
    __syncthreads();

    const int waveId = (blockIdx.x << 2) | w;
    const int nWaves = gridDim.x << 2;

    for (int d = waveId; d < N; d += nWaves) {
        const int base = off[d], end = off[d + 1];
        float pacc[8];
#pragma unroll
        for (int t = 0; t < 8; ++t) pacc[t] = 0.f;

        if (end > base) {
            // prologue: stage chunk-0 perm/src
            {
                int m0 = min(end - base, CH);
                if (l < CH) {
                    int p = perm[base + min(l, m0 - 1)];
                    sPerm[w][0][l] = p;
                    sSrc[w][0][l] = ei[p];
                }
            }
            int buf = 0;
            for (int e0 = base; e0 < end; e0 += CH) {
                const int m = min(end - e0, CH);
                __builtin_amdgcn_wave_barrier();

                // h gathers for this lane's 4 D-rows x 8 col-tiles
                int srcs[4];
#pragma unroll
                for (int ri = 0; ri < 4; ++ri)
                    srcs[ri] = sSrc[w][buf][(kg << 2) + ri];
                float hvv[4][8];
#pragma unroll
                for (int ri = 0; ri < 4; ++ri) {
                    const float* hp = hN + (size_t)srcs[ri] * H + rA;
#pragma unroll
                    for (int t = 0; t < 8; ++t) hvv[ri][t] = hp[t << 4];
                }

                // A loads: this lane's own 2x8 floats of row perm[e0 + rA]
                const int pe = sPerm[w][buf][rA];
                const float* ar = ea + (size_t)pe * ED + (kg << 3);
                float4 a0 = *(const float4*)(ar);
                float4 a1 = *(const float4*)(ar + 4);
                float4 a2 = *(const float4*)(ar + 32);
                float4 a3 = *(const float4*)(ar + 36);

                // prefetch next chunk's perm/src into alternate buffer
                const int e0n = e0 + CH;
                if (e0n < end && l < CH) {
                    int mn = min(end - e0n, CH);
                    int p = perm[e0n + min(l, mn - 1)];
                    sPerm[w][buf ^ 1][l] = p;
                    sSrc[w][buf ^ 1][l] = ei[p];
                }

                // convert A to bf16 fragments
                short8 A0, A1;
                A0[0] = f2bf(a0.x); A0[1] = f2bf(a0.y);
                A0[2] = f2bf(a0.z); A0[3] = f2bf(a0.w);
                A0[4] = f2bf(a1.x); A0[5] = f2bf(a1.y);
                A0[6] = f2bf(a1.z); A0[7] = f2bf(a1.w);
                A1[0] = f2bf(a2.x); A1[1] = f2bf(a2.y);
                A1[2] = f2bf(a2.z); A1[3] = f2bf(a2.w);
                A1[4] = f2bf(a3.x); A1[5] = f2bf(a3.y);
                A1[6] = f2bf(a3.z); A1[7] = f2bf(a3.w);

                // 16 MFMAs: 8 col-tiles x 2 K-steps
                f32x4 C[8];
#pragma unroll
                for (int t = 0; t < 8; ++t) {
                    short8 b0 = *(const short8*)&sBf[t][0][l][0];
                    short8 b1 = *(const short8*)&sBf[t][1][l][0];
                    f32x4 c = __builtin_amdgcn_mfma_f32_16x16x32_bf16(
                        A0, b0, (f32x4){0.f, 0.f, 0.f, 0.f}, 0, 0, 0);
                    C[t] = __builtin_amdgcn_mfma_f32_16x16x32_bf16(
                        A1, b1, c, 0, 0, 0);
                }

                // epilogue: per-edge relu(msg + h) accumulated per column
#pragma unroll
                for (int t = 0; t < 8; ++t) {
#pragma unroll
                    for (int ri = 0; ri < 4; ++ri) {
                        int i = (kg << 2) + ri;
                        float v = C[t][ri] + hvv[ri][t] + beT[t];
                        v = fmaxf(v, 0.f);
                        pacc[t] += (i < m) ? v : 0.f;
                    }
                }
                buf ^= 1;
                __builtin_amdgcn_wave_barrier();
            }
        }
        // reduce the 4 row-groups (lanes l, l^16, l^32, l^48 share a column)
#pragma unroll
        for (int t = 0; t < 8; ++t) {
            float v = pacc[t];
            v += __shfl_xor(v, 16);
            v += __shfl_xor(v, 32);
            pacc[t] = v;
        }
        if (l < 16) {
            float* op = agg + (size_t)d * H + l;
#pragma unroll
            for (int t = 0; t < 8; ++t) op[t << 4] = pacc[t];
        }
    }
}

// ================= Node MLP kernel (1024 thr, bf16 weights in LDS) =================
__global__ __launch_bounds__(1024, 1) void k_mlp(
    const float* __restrict__ hN, float* __restrict__ zb,
    const float* __restrict__ W1, const float* __restrict__ b1,
    const float* __restrict__ W2, const float* __restrict__ b2,
    const float* __restrict__ epsp, int N)
{
    __shared__ unsigned sW1b[H * H / 2];                 // 32 KB
    __shared__ unsigned sW2b[H * H / 2];                 // 32 KB
    __shared__ __align__(16) float sB[16][4][H];         // 32 KB
    __shared__ float sRed[2 * H];
    const int tid = threadIdx.x;
    for (int i = tid; i < H * H / 2; i += 1024) {
        float2 w1 = ((const float2*)W1)[i];
        sW1b[i] = ((unsigned)f2bf(w1.y) << 16) | (unsigned)f2bf(w1.x);
        float2 w2 = ((const float2*)W2)[i];
        sW2b[i] = ((unsigned)f2bf(w2.y) << 16) | (unsigned)f2bf(w2.x);
    }
    if (tid < 2 * H) sRed[tid] = 0.f;
    __syncthreads();

    const int w = tid >> 6, lane = tid & 63;
    const int c = lane << 1;
    const float e1 = 1.f + epsp[0];
    const float2 bb1 = *(const float2*)&b1[c];
    const float2 bb2 = *(const float2*)&b2[c];
    float s0 = 0.f, s1 = 0.f, q0 = 0.f, q1 = 0.f;

    const int waveId = (blockIdx.x << 4) | w;
    const int nWaves = gridDim.x << 4;
    const int nGroups = (N + 3) >> 2;

    float2 hvp[4], avp[4];
    int g0 = waveId;
    if (g0 < nGroups) {
#pragma unroll
        for (int j = 0; j < 4; ++j) {
            int n = min(4 * g0 + j, N - 1);
            size_t o = (size_t)n * H + c;
            hvp[j] = *(const float2*)&hN[o];
            avp[j] = *(const float2*)&zb[o];
        }
    }

    for (int g = g0; g < nGroups; g += nWaves) {
        const int n0 = g << 2;
#pragma unroll
        for (int j = 0; j < 4; ++j) {
            float2 zv;
            zv.x = fmaf(e1, hvp[j].x, avp[j].x);
            zv.y = fmaf(e1, hvp[j].y, avp[j].y);
            *(float2*)&sB[w][j][c] = zv;
        }
        const int gn = g + nWaves;
        if (gn < nGroups) {
#pragma unroll
            for (int j = 0; j < 4; ++j) {
                int n = min(4 * gn + j, N - 1);
                size_t o = (size_t)n * H + c;
                hvp[j] = *(const float2*)&hN[o];
                avp[j] = *(const float2*)&zb[o];
            }
        }
        __builtin_amdgcn_wave_barrier();

        // ---- layer 1
        float ax[4], ay[4];
#pragma unroll
        for (int j = 0; j < 4; ++j) { ax[j] = bb1.x; ay[j] = bb1.y; }
#pragma unroll 4
        for (int k0 = 0; k0 < H; k0 += 4) {
#pragma unroll
            for (int kk = 0; kk < 4; ++kk) {
                unsigned u = sW1b[(k0 + kk) * (H / 2) + lane];
                float wx = __uint_as_float(u << 16);
                float wy = __uint_as_float(u & 0xffff0000u);
#pragma unroll
                for (int j = 0; j < 4; ++j) {
                    float a = sB[w][j][k0 + kk];
                    ax[j] = fmaf(a, wx, ax[j]);
                    ay[j] = fmaf(a, wy, ay[j]);
                }
            }
        }
#pragma unroll
        for (int j = 0; j < 4; ++j) {
            float2 yv;
            yv.x = fmaxf(ax[j], 0.f);
            yv.y = fmaxf(ay[j], 0.f);
            *(float2*)&sB[w][j][c] = yv;
        }
        __builtin_amdgcn_wave_barrier();

        // ---- layer 2
        float cx[4], cy[4];
#pragma unroll
        for (int j = 0; j < 4; ++j) { cx[j] = bb2.x; cy[j] = bb2.y; }
#pragma unroll 4
        for (int k0 = 0; k0 < H; k0 += 4) {
#pragma unroll
            for (int kk = 0; kk < 4; ++kk) {
                unsigned u = sW2b[(k0 + kk) * (H / 2) + lane];
                float wx = __uint_as_float(u << 16);
                float wy = __uint_as_float(u & 0xffff0000u);
#pragma unroll
                for (int j = 0; j < 4; ++j) {
                    float a = sB[w][j][k0 + kk];
                    cx[j] = fmaf(a, wx, cx[j]);
                    cy[j] = fmaf(a, wy, cy[j]);
                }
            }
        }
        __builtin_amdgcn_wave_barrier();

#pragma unroll
        for (int j = 0; j < 4; ++j) {
            int n = n0 + j;
            if (n < N) {
                float z2x = fmaxf(cx[j], 0.f);
                float z2y = fmaxf(cy[j], 0.f);
                size_t o = (size_t)n * H + c;
                float2 ov; ov.x = z2x; ov.y = z2y;
                *(float2*)&zb[o] = ov;
                s0 += z2x; s1 += z2y;
                q0 += z2x * z2x; q1 += z2y * z2y;
            }
        }
        __builtin_amdgcn_wave_barrier();
    }

    __syncthreads();
    atomicAdd(&sRed[c],     s0);
    atomicAdd(&sRed[c + 1], s1);
    atomicAdd(&sRed[H + c],     q0);
    atomicAdd(&sRed[H + c + 1], q1);
    __syncthreads();
    if (tid < H) {
        atomicAdd(&g_stats[tid],     sRed[tid]);
        atomicAdd(&g_stats[H + tid], sRed[H + tid]);
    }
}

__global__ void k_bnfin(const float* __restrict__ gamma, const float* __restrict__ beta,
                        float invN)
{
    int t = threadIdx.x;
    float mean = g_stats[t] * invN;
    float var  = g_stats[H + t] * invN - mean * mean;
    float sc = gamma[t] * rsqrtf(var + 1e-5f);
    g_stats[256 + t] = sc;
    g_stats[384 + t] = beta[t] - mean * sc;
}

__global__ void k_final(const float* __restrict__ hN, const float* __restrict__ valid,
                        float* __restrict__ out, int N)
{
    const int total = N * (H / 4);
    for (int i = blockIdx.x * blockDim.x + threadIdx.x; i < total;
         i += gridDim.x * blockDim.x) {
        int col4 = i & 31;
        int n = i >> 5;
        float4 z = ((float4*)out)[i];
        float4 hv = ((const float4*)hN)[i];
        float4 sc = *(const float4*)&g_stats[256 + col4 * 4];
        float4 sh = *(const float4*)&g_stats[384 + col4 * 4];
        float vf = valid[n];
        float4 r;
        r.x = (hv.x + fmaf(z.x, sc.x, sh.x)) * vf;
        r.y = (hv.y + fmaf(z.y, sc.y, sh.y)) * vf;
        r.z = (hv.z + fmaf(z.z, sc.z, sh.z)) * vf;
        r.w = (hv.w + fmaf(z.w, sc.w, sh.w)) * vf;
        ((float4*)out)[i] = r;
    }
}

// ================= Fallback (ws too small): atomic fp32 edge kernel =================
__global__ __launch_bounds__(256, 4) void k_edge(
    const float* __restrict__ hN, const int* __restrict__ ei,
    const float* __restrict__ ea, const float* __restrict__ We,
    const float* __restrict__ be, float* __restrict__ agg, int E)
{
    __shared__ __align__(16) float sW[ED * H];
    __shared__ __align__(16) float sEA[4][4][ED];
    const int tid = threadIdx.x;
    for (int i = tid; i < (ED * H) / 4; i += 256)
        ((float4*)sW)[i] = ((const float4*)We)[i];
    __syncthreads();
    const int w = tid >> 6, lane = tid & 63;
    const int c = lane << 1;
    const float2 bb = *(const float2*)&be[c];
    const int waveId = (blockIdx.x << 2) | w;
    const int nWaves = gridDim.x << 2;
    const int nGroups = (E + 3) >> 2;
    for (int g = waveId; g < nGroups; g += nWaves) {
        const int e0 = g << 2;
#pragma unroll
        for (int j = 0; j < 4; ++j) {
            int e = e0 + j;
            if (e < E) sEA[w][j][lane] = ea[(size_t)e * ED + lane];
        }
        __builtin_amdgcn_wave_barrier();
        float ax[4], ay[4];
#pragma unroll
        for (int j = 0; j < 4; ++j) { ax[j] = bb.x; ay[j] = bb.y; }
#pragma unroll 4
        for (int k0 = 0; k0 < ED; k0 += 4) {
            const float2 wv0 = *(const float2*)&sW[(k0 + 0) * H + c];
            const float2 wv1 = *(const float2*)&sW[(k0 + 1) * H + c];
            const float2 wv2 = *(const float2*)&sW[(k0 + 2) * H + c];
            const float2 wv3 = *(const float2*)&sW[(k0 + 3) * H + c];
#pragma unroll
            for (int j = 0; j < 4; ++j) {
                const float4 a = *(const float4*)&sEA[w][j][k0];
                ax[j] = fmaf(a.x, wv0.x, ax[j]);
                ay[j] = fmaf(a.x, wv0.y, ay[j]);
                ax[j] = fmaf(a.y, wv1.x, ax[j]);
                ay[j] = fmaf(a.y, wv1.y, ay[j]);
                ax[j] = fmaf(a.z, wv2.x, ax[j]);
                ay[j] = fmaf(a.z, wv2.y, ay[j]);
                ax[j] = fmaf(a.w, wv3.x, ax[j]);
                ay[j] = fmaf(a.w, wv3.y, ay[j]);
            }
        }
#pragma unroll
        for (int j = 0; j < 4; ++j) {
            int e = e0 + j;
            if (e < E) {
                int s = ei[e];
                int d = ei[E + e];
                float2 hv = *(const float2*)&hN[(size_t)s * H + c];
                atomicAdd(&agg[(size_t)d * H + c],     fmaxf(ax[j] + hv.x, 0.f));
                atomicAdd(&agg[(size_t)d * H + c + 1], fmaxf(ay[j] + hv.y, 0.f));
            }
        }
        __builtin_amdgcn_wave_barrier();
    }
}

extern "C" void kernel_launch(void* const* d_in, const int* in_sizes, int n_in,
                              void* d_out, int out_size, void* d_ws, size_t ws_size,
                              hipStream_t stream) {
    const float* hN    = (const float*)d_in[0];
    const int*   ei    = (const int*)d_in[1];
    const float* ea    = (const float*)d_in[2];
    const float* valid = (const float*)d_in[3];
    const float* We    = (const float*)d_in[4];
    const float* be    = (const float*)d_in[5];
    const float* W1    = (const float*)d_in[6];
    const float* b1    = (const float*)d_in[7];
    const float* W2    = (const float*)d_in[8];
    const float* b2    = (const float*)d_in[9];
    const float* epsg  = (const float*)d_in[10];
    const float* gamma = (const float*)d_in[11];
    const float* beta  = (const float*)d_in[12];
    float* out = (float*)d_out;

    const int N = in_sizes[0] / H;
    const int E = in_sizes[1] / 2;

    // workspace layout: cnt[N] | off[N+1] | cur[N] | perm[E]
    const size_t need = ((size_t)N * 3 + 1 + (size_t)E) * sizeof(int);

    k_zero_stats<<<1, 512, 0, stream>>>();

    if (ws_size >= need) {
        int* cnt  = (int*)d_ws;
        int* off  = cnt + N;
        int* cur  = off + N + 1;
        int* perm = cur + N;
        hipMemsetAsync(cnt, 0, (size_t)N * sizeof(int), stream);
        k_hist<<<2048, 256, 0, stream>>>(ei, cnt, E);
        k_scan<<<1, 1024, 0, stream>>>(cnt, off, cur, N);
        k_fill<<<2048, 256, 0, stream>>>(ei, cur, perm, E);
        k_edge_m<<<1024, 256, 0, stream>>>(hN, ei, ea, We, be, off, perm, out, N, E);
    } else {
        hipMemsetAsync(d_out, 0, (size_t)out_size * sizeof(float), stream);
        k_edge<<<2048, 256, 0, stream>>>(hN, ei, ea, We, be, out, E);
    }

    k_mlp<<<256, 1024, 0, stream>>>(hN, out, W1, b1, W2, b2, epsg, N);
    k_bnfin<<<1, 128, 0, stream>>>(gamma, beta, 1.0f / (float)N);
    k_final<<<2048, 256, 0, stream>>>(hN, valid, out, N);
}